// Round 19
// baseline (21543.994 us; speedup 1.0000x reference)
//
#include <hip/hip_runtime.h>

#define T_SEQ 512
#define BB    128
#define HH    512
#define G4    2048
#define KH    512
#define NTHR  256
#define KC    64
#define NCHUNK (KH / KC)   // 8
#define KP    32

typedef unsigned long long u64;
typedef unsigned u32;
typedef unsigned short u16;
typedef __fp16 half2v __attribute__((ext_vector_type(2)));

__device__ __forceinline__ u32 pk2(float a, float b) {
    union { half2v h; u32 u; } t;
    t.h = __builtin_amdgcn_cvt_pkrtz(a, b);
    return t.u;
}
__device__ __forceinline__ float dot2(u32 a, u32 b, float c) {
    union { u32 u; half2v h; } x, y;
    x.u = a; y.u = b;
#if __has_builtin(__builtin_amdgcn_fdot2)
    return __builtin_amdgcn_fdot2(x.h, y.h, c, false);
#else
    return c + (float)x.h.x * (float)y.h.x + (float)x.h.y * (float)y.h.y;
#endif
}
__device__ __forceinline__ u16 f2h(float v) {
    union { __fp16 h; u16 u; } cv; cv.h = (__fp16)v; return cv.u;
}
__device__ __forceinline__ float h2f(u16 v) {
    union { u16 u; __fp16 h; } cv; cv.u = v; return (float)cv.h;
}

// ===== pack Wih (proven) + bsum =============================================
__global__ __launch_bounds__(256)
void pack_wx(const float* __restrict__ Wih,
             const float* __restrict__ bih, const float* __restrict__ bhh,
             u32* __restrict__ WpX, float* __restrict__ bsum)
{
    __shared__ float tile[64][65];
    const int tid = threadIdx.x;
    const int blk = blockIdx.x;          // 0..511
    if (blk < 16) bsum[blk * 256 + tid] = bih[blk * 256 + tid] + bhh[blk * 256 + tid];

    const int kc = blk & 7;
    const int nt = (blk >> 3) & 31;
    const int l  = blk >> 8;

    const int c  = tid >> 2;
    const int ko = (tid & 3) * 16;
    const int grow = nt * 64 + c;
    const float* src = Wih + ((size_t)(l * G4 + grow)) * 512 + kc * 64 + ko;
    #pragma unroll
    for (int it = 0; it < 4; ++it) {
        float4 v = ((const float4*)src)[it];
        tile[c][ko + 4*it + 0] = v.x;
        tile[c][ko + 4*it + 1] = v.y;
        tile[c][ko + 4*it + 2] = v.z;
        tile[c][ko + 4*it + 3] = v.w;
    }
    __syncthreads();
    const int kp = tid >> 3;
    const int cb = (tid & 7) * 8;
    u32* dst = WpX + ((size_t)((l * 32 + nt) * 256) + kc * 32 + kp) * 64 + cb;
    #pragma unroll
    for (int j = 0; j < 8; ++j)
        dst[j] = pk2(tile[cb + j][2 * kp], tile[cb + j][2 * kp + 1]);
}

// ===== pack Whh lane-major (proven; 2^18 threads -> grid 1024) ==============
__global__ __launch_bounds__(256)
void pack_wh2(const float* __restrict__ Whh, u32* __restrict__ Wp2)
{
    const int flat = blockIdx.x * 256 + threadIdx.x;   // 0..262143
    const int tp = flat & 511;
    const int j  = (flat >> 9) & 3;
    const int g  = (flat >> 11) & 3;
    const int kc = (flat >> 13) & 15;
    const int l  = (flat >> 17) & 1;
    const float* src = Whh + ((size_t)(l * G4 + g * 512 + tp)) * 512 + kc * 32 + j * 8;
    float4 a = ((const float4*)src)[0];
    float4 b = ((const float4*)src)[1];
    u32* dst = Wp2 + ((size_t)(((l * 16 + kc) * 4 + g) * 4 + j) * 512 + tp) * 4;
    dst[0] = pk2(a.x, a.y); dst[1] = pk2(a.z, a.w);
    dst[2] = pk2(b.x, b.y); dst[3] = pk2(b.z, b.w);
}

// ===== Prepass (proven): gxbuf[t][b][2048] f16 = Xin[b][t] @ Wih^T ==========
__global__ __launch_bounds__(NTHR)
void prepass_gx(const float* __restrict__ Xin,
                const u32* __restrict__ WpXl,
                u16* __restrict__ gxbuf)
{
    __shared__ u32 As2[KP][34];
    __shared__ u32 Bs[KP * 64];
    const int tid = threadIdx.x;
    const int blk = blockIdx.x;
    const int nt = blk & 31;
    const int tg = (blk >> 5) & 15;
    const int b  = blk >> 9;
    const int t0 = tg * 32;
    const int xr = tid >> 4, xc4 = tid & 15;
    const int ty = tid >> 4, tx = tid & 15;
    const u32* Wp = WpXl + (size_t)nt * (256 * 64);
    const float* Ab = Xin + ((size_t)b * T_SEQ + t0) * 512;

    float4 vaX[2][2];
    uint4  vb16[2];
    float acc[2][4] = {};

    auto loadA = [&](int c, int s) {
        #pragma unroll
        for (int it = 0; it < 2; ++it)
            vaX[s][it] = *(const float4*)(Ab + (size_t)(xr + 16*it) * 512 + c * KC + 4 * xc4);
    };
    auto loadB = [&](int c) {
        const uint4* q = (const uint4*)(Wp + (size_t)c * (KP * 64));
        vb16[0] = q[tid];
        vb16[1] = q[tid + 256];
    };

    loadA(0, 0);
    loadB(0);
    loadA(1, 1);
    for (int c = 0; c < NCHUNK; ++c) {
        __syncthreads();
        #pragma unroll
        for (int it = 0; it < 2; ++it) {
            const float4 v = vaX[c & 1][it];
            As2[2*xc4+0][xr+16*it] = pk2(v.x, v.y);
            As2[2*xc4+1][xr+16*it] = pk2(v.z, v.w);
        }
        ((uint4*)Bs)[tid]       = vb16[0];
        ((uint4*)Bs)[tid + 256] = vb16[1];
        __syncthreads();
        if (c + 2 < NCHUNK) loadA(c + 2, c & 1);
        if (c + 1 < NCHUNK) loadB(c + 1);
        #pragma unroll
        for (int kp = 0; kp < KP; ++kp) {
            uint2 a = *(const uint2*)&As2[kp][2 * ty];
            uint4 bq = *(const uint4*)&Bs[kp * 64 + 4 * tx];
            acc[0][0] = dot2(a.x, bq.x, acc[0][0]);
            acc[0][1] = dot2(a.x, bq.y, acc[0][1]);
            acc[0][2] = dot2(a.x, bq.z, acc[0][2]);
            acc[0][3] = dot2(a.x, bq.w, acc[0][3]);
            acc[1][0] = dot2(a.y, bq.x, acc[1][0]);
            acc[1][1] = dot2(a.y, bq.y, acc[1][1]);
            acc[1][2] = dot2(a.y, bq.z, acc[1][2]);
            acc[1][3] = dot2(a.y, bq.w, acc[1][3]);
        }
    }
    #pragma unroll
    for (int r = 0; r < 2; ++r) {
        const int t = t0 + 2 * ty + r;
        const u64 w = (u64)f2h(acc[r][0])
                    | ((u64)f2h(acc[r][1]) << 16)
                    | ((u64)f2h(acc[r][2]) << 32)
                    | ((u64)f2h(acc[r][3]) << 48);
        *(u64*)(gxbuf + ((size_t)t * BB + b) * G4 + nt * 64 + 4 * tx) = w;
    }
}

// ===== Row-owner recurrence v3: 128 blocks x 1024 thr, ONE row per block ====
// Zero inter-block sync (proven protocol). vs R17/R18 (null at 512 thr): 16
// waves/CU instead of 8 -> 2x independent load chains per CU; per-thread
// weight stream halves to 128 uint4/step. Thread layout: col = tid&511;
// lower half (tid<512) owns gates {i=0, c=2}, upper half owns {f=1, o=3} --
// the needed uint4 indices are a SUBSET of the proven Wp2 layout (no repack).
// f,o raw gates cross the halves via LDS inside the existing 2 syncs/step.
__global__ __launch_bounds__(1024, 1)
void lstm_rec3(const u16* __restrict__ gxbuf,
               const u32* __restrict__ Wp2l,    // [16][4][4][512] uint4
               const float* __restrict__ bsl,   // [2048]
               const float* __restrict__ c0l,   // idx row*1024 + j
               const float* __restrict__ h0l,   // idx row*1024 + j
               float* __restrict__ Out)         // [B][T][512]
{
    __shared__ __align__(16) u16 hsh[512];
    __shared__ float gfo[2][512];
    __shared__ float red[16][4];

    const int tid = threadIdx.x;     // 0..1023
    const int row = blockIdx.x;      // 0..127
    const int col = tid & 511;
    const int hi  = tid >> 9;        // 0: gates {0,2}; 1: gates {1,3}
    const int gA  = hi;              // i or f
    const int gB  = hi + 2;          // c or o

    float cst = 0.f, bv[2];
    bv[0] = bsl[gA * 512 + col];
    bv[1] = bsl[gB * 512 + col];
    if (!hi) {
        cst = c0l[(size_t)row * 1024 + col];
        hsh[col] = f2h(h0l[(size_t)row * 1024 + col]);
    }
    __syncthreads();

    const uint4* Wq = (const uint4*)Wp2l;
    // uint4 index for (kc, g, j): (kc*16 + g*4 + j)*512 + col
    const int iA = gA * 4;           // base i for gate A (j 0..3)
    const int iB = gB * 4;

    uint4 wc[8], wn[8];
    #pragma unroll
    for (int j = 0; j < 4; ++j) {
        wc[j]     = Wq[(size_t)(iA + j) * 512 + col];
        wc[4 + j] = Wq[(size_t)(iB + j) * 512 + col];
    }

    for (int t = 0; t < T_SEQ; ++t) {
        const u16* gp = gxbuf + ((size_t)t * BB + row) * G4;
        float gxv[2];
        gxv[0] = h2f(gp[(size_t)gA * 512 + col]);
        gxv[1] = h2f(gp[(size_t)gB * 512 + col]);

        float acc[2] = {0.f, 0.f};

        #define COMPUTE_CHUNK(KCC, WREG)                                     \
        {                                                                    \
            u32 hr[16];                                                      \
            _Pragma("unroll")                                                \
            for (int q = 0; q < 4; ++q)                                      \
                *(uint4*)&hr[q * 4] =                                        \
                    *(const uint4*)&((const u32*)hsh)[(KCC) * 16 + q * 4];   \
            _Pragma("unroll")                                                \
            for (int a = 0; a < 2; ++a) {                                    \
                _Pragma("unroll")                                            \
                for (int j = 0; j < 4; ++j) {                                \
                    const uint4 w = WREG[a * 4 + j];                         \
                    acc[a] = dot2(hr[j*4+0], w.x, acc[a]);                   \
                    acc[a] = dot2(hr[j*4+1], w.y, acc[a]);                   \
                    acc[a] = dot2(hr[j*4+2], w.z, acc[a]);                   \
                    acc[a] = dot2(hr[j*4+3], w.w, acc[a]);                   \
                }                                                            \
            }                                                                \
        }

        #pragma unroll 1
        for (int kc = 0; kc < 16; kc += 2) {
            #pragma unroll
            for (int j = 0; j < 4; ++j) {
                wn[j]     = Wq[(size_t)((kc + 1) * 16 + iA + j) * 512 + col];
                wn[4 + j] = Wq[(size_t)((kc + 1) * 16 + iB + j) * 512 + col];
            }
            COMPUTE_CHUNK(kc, wc)
            #pragma unroll
            for (int j = 0; j < 4; ++j) {
                wc[j]     = Wq[(size_t)(((kc + 2) & 15) * 16 + iA + j) * 512 + col];
                wc[4 + j] = Wq[(size_t)(((kc + 2) & 15) * 16 + iB + j) * 512 + col];
            }
            COMPUTE_CHUNK(kc + 1, wn)
        }
        #undef COMPUTE_CHUNK

        // gates + block-local L1 norms
        const float gvA = acc[0] + gxv[0] + bv[0];   // i (lower) / f (upper)
        const float gvB = acc[1] + gxv[1] + bv[1];   // c (lower) / o (upper)
        float p0 = hi ? 0.f : fabsf(gvA);            // |i|
        float p1 = hi ? fabsf(gvA) : 0.f;            // |f|
        float p2 = hi ? fabsf(gvB) : 0.f;            // |o|
        #pragma unroll
        for (int d = 1; d < 64; d <<= 1) {
            p0 += __shfl_xor(p0, d);
            p1 += __shfl_xor(p1, d);
            p2 += __shfl_xor(p2, d);
        }
        const int wv = tid >> 6;
        if ((tid & 63) == 0) {
            red[wv][0] = p0; red[wv][1] = p1; red[wv][2] = p2;
        }
        if (hi) {
            gfo[0][col] = gvA;   // raw f
            gfo[1][col] = gvB;   // raw o
        }
        __syncthreads();   // norms + gfo visible; GEMM reads of hsh done

        if (!hi) {
            float S0 = 0.f, S1 = 0.f, S2 = 0.f;
            #pragma unroll
            for (int w = 0; w < 16; ++w) {
                S0 += red[w][0]; S1 += red[w][1]; S2 += red[w][2];
            }
            S0 = fmaxf(S0, 1e-12f);
            S1 = fmaxf(S1, 1e-12f);
            S2 = fmaxf(S2, 1e-12f);
            const float iv = 1.f / (1.f + expf(-gvA / S0));
            const float fv = 1.f / (1.f + expf(-gfo[0][col] / S1));
            const float ov = 1.f / (1.f + expf(-gfo[1][col] / S2));
            const float cn = fv * cst + iv * gvB;
            cst = cn;
            const float hn = ov * fmaxf(cn, 0.f);
            Out[((size_t)row * T_SEQ + t) * 512 + col] = hn;
            hsh[col] = f2h(hn);
        }
        __syncthreads();   // h(t) visible to next step's GEMM
    }
}

extern "C" void kernel_launch(void* const* d_in, const int* in_sizes, int n_in,
                              void* d_out, int out_size, void* d_ws, size_t ws_size,
                              hipStream_t stream)
{
    const float* x   = (const float*)d_in[0];
    const float* h0  = (const float*)d_in[1];
    const float* c0  = (const float*)d_in[2];
    const float* Wih = (const float*)d_in[3];
    const float* bih = (const float*)d_in[4];
    const float* Whh = (const float*)d_in[5];
    const float* bhh = (const float*)d_in[6];
    float* out = (float*)d_out;
    float* ws  = (float*)d_ws;

    // ws layout identical to R16/R17/R18 (proven)
    float* part  = ws + 1024;                   // (unused)
    float* hbuf  = part + 16384;                // (unused)
    u32*   WpX   = (u32*)(hbuf + 65536);        // 1048576 u32 (2 layers)
    u32*   Wp2   = WpX + 1048576;               // 1048576 u32 (2 layers)
    float* bsum  = (float*)(Wp2 + 1048576);     // 4096 f
    u16*   gxbuf = (u16*)(bsum + 4096);         // 256 MB
    (void)ws_size;

    hipLaunchKernelGGL(pack_wx, dim3(512), dim3(256), 0, stream,
                       Wih, bih, bhh, WpX, bsum);
    hipLaunchKernelGGL(pack_wh2, dim3(1024), dim3(256), 0, stream,
                       Whh, Wp2);

    for (int l = 0; l < 2; ++l) {
        const float* Xin = (l == 0) ? x : (const float*)out;
        hipLaunchKernelGGL(prepass_gx, dim3(65536), dim3(256), 0, stream,
                           Xin, WpX + (size_t)l * 524288, gxbuf);
        hipLaunchKernelGGL(lstm_rec3, dim3(128), dim3(1024), 0, stream,
                           gxbuf, Wp2 + (size_t)l * 524288,
                           bsum + l * 2048, c0 + l * 512, h0 + l * 512, out);
    }
}

// Round 21
// 16345.070 us; speedup vs baseline: 1.3181x; 1.3181x over previous
//
#include <hip/hip_runtime.h>

#define T_SEQ 512
#define BB    128
#define HH    512
#define G4    2048

typedef unsigned long long u64;
typedef unsigned u32;
typedef unsigned short u16;
typedef __fp16 half2v __attribute__((ext_vector_type(2)));
typedef __fp16 half8 __attribute__((ext_vector_type(8)));
typedef float  f32x4 __attribute__((ext_vector_type(4)));

__device__ __forceinline__ u32 pk2(float a, float b) {
    union { half2v h; u32 u; } t;
    t.h = __builtin_amdgcn_cvt_pkrtz(a, b);
    return t.u;
}
__device__ __forceinline__ float dot2(u32 a, u32 b, float c) {
    union { u32 u; half2v h; } x, y;
    x.u = a; y.u = b;
#if __has_builtin(__builtin_amdgcn_fdot2)
    return __builtin_amdgcn_fdot2(x.h, y.h, c, false);
#else
    return c + (float)x.h.x * (float)y.h.x + (float)x.h.y * (float)y.h.y;
#endif
}
__device__ __forceinline__ u16 f2h(float v) {
    union { __fp16 h; u16 u; } cv; cv.h = (__fp16)v; return cv.u;
}
__device__ __forceinline__ float h2f(u16 v) {
    union { u16 u; __fp16 h; } cv; cv.u = v; return (float)cv.h;
}

// ===== bias sum =============================================================
__global__ __launch_bounds__(256)
void bsum_k(const float* __restrict__ bih, const float* __restrict__ bhh,
            float* __restrict__ bsum)
{
    const int i = blockIdx.x * 256 + threadIdx.x;   // 0..4095
    bsum[i] = bih[i] + bhh[i];
}

// ===== pack Whh lane-major (proven; 2^18 threads -> grid 1024) ==============
__global__ __launch_bounds__(256)
void pack_wh2(const float* __restrict__ Whh, u32* __restrict__ Wp2)
{
    const int flat = blockIdx.x * 256 + threadIdx.x;   // 0..262143
    const int tp = flat & 511;
    const int j  = (flat >> 9) & 3;
    const int g  = (flat >> 11) & 3;
    const int kc = (flat >> 13) & 15;
    const int l  = (flat >> 17) & 1;
    const float* src = Whh + ((size_t)(l * G4 + g * 512 + tp)) * 512 + kc * 32 + j * 8;
    float4 a = ((const float4*)src)[0];
    float4 b = ((const float4*)src)[1];
    u32* dst = Wp2 + ((size_t)(((l * 16 + kc) * 4 + g) * 4 + j) * 512 + tp) * 4;
    dst[0] = pk2(a.x, a.y); dst[1] = pk2(a.z, a.w);
    dst[2] = pk2(b.x, b.y); dst[3] = pk2(b.z, b.w);
}

// ===== MFMA prepass: gxbuf[m][n] f16, m = t*128+b, n = gate col =============
// C[65536,2048] = A @ B^T_op;  A[m][k] = Xin[b][t][k],  Bop[n][k] = Wih[n][k].
// Block: 256 thr / 4 waves; tile M=64 x N=128; K-step 32; f16 in, f32 acc.
// Fragments (guide-verified gfx950 16x16x32): A/B idx=lane&15, k=(lane>>4)*8+j;
// D col=lane&15, row=(lane>>4)*4+reg.
__global__ __launch_bounds__(256)
void prepass_mfma(const float* __restrict__ Xin,
                  const float* __restrict__ WihL,   // [2048][512] f32
                  u16* __restrict__ gxbuf)
{
    __shared__ u32 Ash[64 * 20];    // [64 rows][40 f16 padded]
    __shared__ u32 Bsh[128 * 20];   // Bop[n][k] [128][40 f16 padded]

    const int tid = threadIdx.x;
    const int blk = blockIdx.x;          // 0..16383 = mt*16 + nt4
    const int mt  = blk >> 4;
    const int n0  = (blk & 15) * 128;
    const int m0  = mt * 64;
    const int b0  = (mt & 1) * 64;
    const int t0  = mt >> 1;

    const int lane = tid & 63;
    const int wave = tid >> 6;
    const int wm = wave >> 1, wn = wave & 1;
    const int lr = lane & 15, lk = lane >> 4;

    const int ai = tid >> 2, aq = tid & 3;   // A staging: row, k-eighth
    const int bn = tid >> 1, bq = tid & 1;   // B staging: n-row, k-half

    f32x4 acc[2][4];
    #pragma unroll
    for (int s = 0; s < 2; ++s)
        #pragma unroll
        for (int c = 0; c < 4; ++c) acc[s][c] = (f32x4)(0.f);

    const float* Arow = Xin + ((size_t)(b0 + ai) * T_SEQ + t0) * 512 + aq * 8;
    const float* Brow = WihL + (size_t)(n0 + bn) * 512 + bq * 16;

    union U4H8 { uint4 u; half8 h; };

    for (int kc = 0; kc < 16; ++kc) {
        const int k0 = kc * 32;
        const float4 a0 = *(const float4*)(Arow + k0);
        const float4 a1 = *(const float4*)(Arow + k0 + 4);
        const float4 w0 = *(const float4*)(Brow + k0);
        const float4 w1 = *(const float4*)(Brow + k0 + 4);
        const float4 w2 = *(const float4*)(Brow + k0 + 8);
        const float4 w3 = *(const float4*)(Brow + k0 + 12);
        __syncthreads();   // prior iter's frag reads done before overwrite
        *(uint4*)&Ash[ai * 20 + aq * 4] =
            make_uint4(pk2(a0.x, a0.y), pk2(a0.z, a0.w), pk2(a1.x, a1.y), pk2(a1.z, a1.w));
        *(uint4*)&Bsh[bn * 20 + bq * 8] =
            make_uint4(pk2(w0.x, w0.y), pk2(w0.z, w0.w), pk2(w1.x, w1.y), pk2(w1.z, w1.w));
        *(uint4*)&Bsh[bn * 20 + bq * 8 + 4] =
            make_uint4(pk2(w2.x, w2.y), pk2(w2.z, w2.w), pk2(w3.x, w3.y), pk2(w3.z, w3.w));
        __syncthreads();

        U4H8 af[2], bf[4];
        #pragma unroll
        for (int s = 0; s < 2; ++s)
            af[s].u = *(const uint4*)&Ash[(wm * 32 + s * 16 + lr) * 20 + lk * 4];
        #pragma unroll
        for (int c = 0; c < 4; ++c)
            bf[c].u = *(const uint4*)&Bsh[(wn * 64 + c * 16 + lr) * 20 + lk * 4];

        #pragma unroll
        for (int s = 0; s < 2; ++s)
            #pragma unroll
            for (int c = 0; c < 4; ++c)
                acc[s][c] = __builtin_amdgcn_mfma_f32_16x16x32_f16(
                    af[s].h, bf[c].h, acc[s][c], 0, 0, 0);
    }

    #pragma unroll
    for (int s = 0; s < 2; ++s) {
        #pragma unroll
        for (int c = 0; c < 4; ++c) {
            #pragma unroll
            for (int r = 0; r < 4; ++r) {
                const int row  = wm * 32 + s * 16 + (lane >> 4) * 4 + r;
                const int coln = wn * 64 + c * 16 + (lane & 15);
                gxbuf[(size_t)(m0 + row) * G4 + n0 + coln] = f2h(acc[s][c][r]);
            }
        }
    }
}

// ===== Row-owner recurrence (R18 verbatim, proven): 128 blocks x 512 thr ====
__global__ __launch_bounds__(512, 1)
void lstm_rec2(const u16* __restrict__ gxbuf,
               const u32* __restrict__ Wp2l,    // [16][4][4][512] uint4
               const float* __restrict__ bsl,   // [2048]
               const float* __restrict__ c0l,   // idx row*1024 + j
               const float* __restrict__ h0l,   // idx row*1024 + j
               float* __restrict__ Out)         // [B][T][512]
{
    __shared__ __align__(16) u16 hsh[512];
    __shared__ float red[8][8];

    const int tid = threadIdx.x;     // 0..511
    const int row = blockIdx.x;      // 0..127

    float cst, bv[4];
    cst = c0l[(size_t)row * 1024 + tid];
    #pragma unroll
    for (int g = 0; g < 4; ++g) bv[g] = bsl[g * 512 + tid];
    hsh[tid] = f2h(h0l[(size_t)row * 1024 + tid]);
    __syncthreads();

    const uint4* Wq = (const uint4*)Wp2l;

    uint4 wc[16], wn[16];
    #pragma unroll
    for (int i = 0; i < 16; ++i) wc[i] = Wq[(size_t)i * 512 + tid];

    for (int t = 0; t < T_SEQ; ++t) {
        const u16* gp = gxbuf + ((size_t)t * BB + row) * G4;
        float gxv[4];
        #pragma unroll
        for (int g = 0; g < 4; ++g) gxv[g] = h2f(gp[(size_t)g * 512 + tid]);

        float acc[4] = {0.f, 0.f, 0.f, 0.f};

        #define COMPUTE_CHUNK(KCC, WREG)                                     \
        {                                                                    \
            u32 hr[16];                                                      \
            _Pragma("unroll")                                                \
            for (int q = 0; q < 4; ++q)                                      \
                *(uint4*)&hr[q * 4] =                                        \
                    *(const uint4*)&((const u32*)hsh)[(KCC) * 16 + q * 4];   \
            _Pragma("unroll")                                                \
            for (int g = 0; g < 4; ++g) {                                    \
                _Pragma("unroll")                                            \
                for (int j = 0; j < 4; ++j) {                                \
                    const uint4 w = WREG[g * 4 + j];                         \
                    acc[g] = dot2(hr[j*4+0], w.x, acc[g]);                   \
                    acc[g] = dot2(hr[j*4+1], w.y, acc[g]);                   \
                    acc[g] = dot2(hr[j*4+2], w.z, acc[g]);                   \
                    acc[g] = dot2(hr[j*4+3], w.w, acc[g]);                   \
                }                                                            \
            }                                                                \
        }

        #pragma unroll 1
        for (int kc = 0; kc < 16; kc += 2) {
            #pragma unroll
            for (int i = 0; i < 16; ++i)
                wn[i] = Wq[(size_t)((kc + 1) * 16 + i) * 512 + tid];
            COMPUTE_CHUNK(kc, wc)
            #pragma unroll
            for (int i = 0; i < 16; ++i)
                wc[i] = Wq[(size_t)((((kc + 2) & 15)) * 16 + i) * 512 + tid];
            COMPUTE_CHUNK(kc + 1, wn)
        }
        #undef COMPUTE_CHUNK

        float gv[4], pv[3];
        #pragma unroll
        for (int g = 0; g < 4; ++g) gv[g] = acc[g] + gxv[g] + bv[g];
        pv[0] = fabsf(gv[0]);
        pv[1] = fabsf(gv[1]);
        pv[2] = fabsf(gv[3]);
        #pragma unroll
        for (int d = 1; d < 64; d <<= 1)
            #pragma unroll
            for (int q = 0; q < 3; ++q) pv[q] += __shfl_xor(pv[q], d);
        const int wv = tid >> 6;
        if ((tid & 63) == 0) {
            #pragma unroll
            for (int q = 0; q < 3; ++q) red[wv][q] = pv[q];
        }
        __syncthreads();
        float S[3];
        #pragma unroll
        for (int q = 0; q < 3; ++q) {
            float s = 0.f;
            #pragma unroll
            for (int w = 0; w < 8; ++w) s += red[w][q];
            S[q] = fmaxf(s, 1e-12f);
        }
        const float iv = 1.f / (1.f + expf(-gv[0] / S[0]));
        const float fv = 1.f / (1.f + expf(-gv[1] / S[1]));
        const float ov = 1.f / (1.f + expf(-gv[3] / S[2]));
        const float cn = fv * cst + iv * gv[2];
        cst = cn;
        const float hn = ov * fmaxf(cn, 0.f);
        Out[((size_t)row * T_SEQ + t) * 512 + tid] = hn;
        hsh[tid] = f2h(hn);
        __syncthreads();
    }
}

extern "C" void kernel_launch(void* const* d_in, const int* in_sizes, int n_in,
                              void* d_out, int out_size, void* d_ws, size_t ws_size,
                              hipStream_t stream)
{
    const float* x   = (const float*)d_in[0];
    const float* h0  = (const float*)d_in[1];
    const float* c0  = (const float*)d_in[2];
    const float* Wih = (const float*)d_in[3];
    const float* bih = (const float*)d_in[4];
    const float* Whh = (const float*)d_in[5];
    const float* bhh = (const float*)d_in[6];
    float* out = (float*)d_out;
    float* ws  = (float*)d_ws;

    // ws layout identical to R16-R19 (proven); WpX region now unused.
    float* part  = ws + 1024;                   // (unused)
    float* hbuf  = part + 16384;                // (unused)
    u32*   WpX   = (u32*)(hbuf + 65536);        // (unused, kept for offsets)
    u32*   Wp2   = WpX + 1048576;               // 1048576 u32 (2 layers)
    float* bsum  = (float*)(Wp2 + 1048576);     // 4096 f
    u16*   gxbuf = (u16*)(bsum + 4096);         // 256 MB
    (void)ws_size;

    hipLaunchKernelGGL(bsum_k, dim3(16), dim3(256), 0, stream, bih, bhh, bsum);
    hipLaunchKernelGGL(pack_wh2, dim3(1024), dim3(256), 0, stream, Whh, Wp2);

    for (int l = 0; l < 2; ++l) {
        const float* Xin  = (l == 0) ? x : (const float*)out;
        const float* WihL = Wih + (size_t)l * G4 * 512;
        hipLaunchKernelGGL(prepass_mfma, dim3(16384), dim3(256), 0, stream,
                           Xin, WihL, gxbuf);
        hipLaunchKernelGGL(lstm_rec2, dim3(128), dim3(512), 0, stream,
                           gxbuf, Wp2 + (size_t)l * 524288,
                           bsum + l * 2048, c0 + l * 512, h0 + l * 512, out);
    }
}